// Round 1
// 702.515 us; speedup vs baseline: 1.8782x; 1.8782x over previous
//
#include <hip/hip_runtime.h>

// ---------------------------------------------------------------------------
// LiteTracker correlation-pyramid hot path. FP32 in/out, bf16 internal staging.
// Pipelined fused-stage schedule: launch t runs corr(t) || gemm1(t-1) ||
// gemm2(t-2) in one heterogeneous grid with double-buffered X / H.
// Workspace-size adaptive:
//   ws >= 52.4 MB : CHUNK=4096 (whole level per stage), 6 launches total
//   ws >= 17.8 MB : CHUNK=1024, 18 launches
//   else          : CHUNK=1024 sequential fallback (48 launches)
// ---------------------------------------------------------------------------

typedef __bf16 bf16x8 __attribute__((ext_vector_type(8)));
typedef float f32x4 __attribute__((ext_vector_type(4)));

#define KPAD 2432          // 2401 padded to 76*32
#define K_RAW 2401
#define NPTS 4096

__device__ __forceinline__ float b2f(unsigned short u) {
    return __uint_as_float(((unsigned int)u) << 16);
}
__device__ __forceinline__ unsigned short f2b(float f) {
    unsigned int u = __float_as_uint(f);
    u += 0x7fffu + ((u >> 16) & 1u);   // round-to-nearest-even
    return (unsigned short)(u >> 16);
}
__device__ __forceinline__ void unpack8(uint4 v, float* f) {
    f[0] = b2f((unsigned short)(v.x & 0xffffu)); f[1] = b2f((unsigned short)(v.x >> 16));
    f[2] = b2f((unsigned short)(v.y & 0xffffu)); f[3] = b2f((unsigned short)(v.y >> 16));
    f[4] = b2f((unsigned short)(v.z & 0xffffu)); f[5] = b2f((unsigned short)(v.z >> 16));
    f[6] = b2f((unsigned short)(v.w & 0xffffu)); f[7] = b2f((unsigned short)(v.w >> 16));
}
__device__ __forceinline__ uint4 pack8(const float* f) {
    unsigned short pk[8];
#pragma unroll
    for (int j = 0; j < 8; ++j) pk[j] = f2b(f[j]);
    uint4 o;
    o.x = pk[0] | ((unsigned int)pk[1] << 16);
    o.y = pk[2] | ((unsigned int)pk[3] << 16);
    o.z = pk[4] | ((unsigned int)pk[5] << 16);
    o.w = pk[6] | ((unsigned int)pk[7] << 16);
    return o;
}

// ---------------------------------------------------------------------------
// k_prep. Region A: fmap transpose, source-linear. Regions B/C: weight
// transposes, dest-linear. total elems 3,121,152 -> grid 12192 x 256
// ---------------------------------------------------------------------------
__global__ __launch_bounds__(256) void k_prep(
    const float* __restrict__ f0, const float* __restrict__ f1,
    const float* __restrict__ f2, const float* __restrict__ f3,
    const float* __restrict__ w1, const float* __restrict__ w2,
    unsigned short* __restrict__ fmapT, unsigned short* __restrict__ W1T,
    unsigned short* __restrict__ W2T)
{
    int idx = blockIdx.x * 256 + threadIdx.x;
    const int FT = 2088960;
    if (idx < FT) {
        int off, HW;
        const float* src;
        if (idx < 1572864)      { off = 0;       HW = 12288; src = f0; }
        else if (idx < 1966080) { off = 1572864; HW = 3072;  src = f1; }
        else if (idx < 2064384) { off = 1966080; HW = 768;   src = f2; }
        else                    { off = 2064384; HW = 192;   src = f3; }
        int r = idx - off;
        int c = r / HW, p = r - c * HW;          // src layout [128][HW]
        fmapT[off + p * 128 + c] = f2b(src[r]);  // dst layout [HW][128]
    } else if (idx < FT + 933888) {
        int j = idx - FT;
        int n = j / KPAD, k = j - n * KPAD;
        W1T[j] = (k < K_RAW) ? f2b(w1[k * 384 + n]) : (unsigned short)0;
    } else if (idx < FT + 933888 + 98304) {
        int j = idx - (FT + 933888);
        int n = j / 384, k = j - n * 384;
        W2T[j] = f2b(w2[k * 256 + n]);
    }
}

// ---------------------------------------------------------------------------
// corr body: one block (256 thr, 4 waves) per point.
//   fA[64][136] bf16: bilinear support feats ; fB[64][136] bf16: template
//   S = fA . fB^T via 16x16x32 bf16 MFMA; writes one X row (2432, padded).
// ---------------------------------------------------------------------------
__device__ __forceinline__ void corr_body(unsigned short* sm, int bb,
    const unsigned short* __restrict__ fm,   // level's [H*W,128] bf16 fmapT
    const float* __restrict__ tf,            // level's tfeat fp32 [49,4096,128]
    const float* __restrict__ coords,        // fp32 [4096,2]
    unsigned short* __restrict__ X,          // [CH, 2432] bf16
    int W, int H, float scale, int n0)
{
    unsigned short* fA = sm;
    unsigned short* fB = sm + 64 * 136;
    const int tid = threadIdx.x;
    const int nl = bb;                 // local row in chunk
    const int n  = n0 + nl;            // global point id

    const float px = coords[2 * n]     * scale;
    const float py = coords[2 * n + 1] * scale;

    // zero pad rows 49..63 of both LDS arrays
    for (int i = tid; i < 2040; i += 256) {
        fA[49 * 136 + i] = 0;
        fB[49 * 136 + i] = 0;
    }
    // stage template (fp32 -> bf16): 49 rows x 16 chunks of 8 ch
    for (int i = tid; i < 784; i += 256) {
        int g = i >> 4, c8 = i & 15;
        const float* p = tf + (size_t)g * (NPTS * 128) + (size_t)n * 128 + c8 * 8;
        float v[8];
#pragma unroll
        for (int j = 0; j < 8; ++j) v[j] = p[j];
        *reinterpret_cast<uint4*>(&fB[g * 136 + c8 * 8]) = pack8(v);
    }
    // bilinear gather into fA: sample s=(a,b): x-offset a-3, y-offset b-3
    for (int i = tid; i < 784; i += 256) {
        int s = i >> 4, c8 = i & 15;
        int a = s / 7, b = s - a * 7;
        float sx = px + (float)(a - 3);
        float sy = py + (float)(b - 3);
        float x0f = floorf(sx), y0f = floorf(sy);
        float wx = sx - x0f, wy = sy - y0f;
        int x0 = (int)x0f, y0 = (int)y0f;
        float acc[8] = {0.f, 0.f, 0.f, 0.f, 0.f, 0.f, 0.f, 0.f};
#pragma unroll
        for (int dy = 0; dy < 2; ++dy) {
            int yi = y0 + dy;
            if (yi < 0 || yi >= H) continue;
            float wyv = dy ? wy : 1.0f - wy;
#pragma unroll
            for (int dx = 0; dx < 2; ++dx) {
                int xi = x0 + dx;
                if (xi < 0 || xi >= W) continue;
                float wv = wyv * (dx ? wx : 1.0f - wx);
                uint4 v = *reinterpret_cast<const uint4*>(
                    fm + (size_t)(yi * W + xi) * 128 + c8 * 8);
                float f[8]; unpack8(v, f);
#pragma unroll
                for (int j = 0; j < 8; ++j) acc[j] += wv * f[j];
            }
        }
        *reinterpret_cast<uint4*>(&fA[s * 136 + c8 * 8]) = pack8(acc);
    }
    unsigned short* Xrow = X + (size_t)nl * KPAD;
    if (tid < 31) Xrow[K_RAW + tid] = 0;   // zero K padding
    __syncthreads();

    // MFMA: wave w -> S rows [16w,16w+16); 4 col tiles; K=128 in 4 steps
    const int wave = tid >> 6, lane = tid & 63;
    const int la = lane & 15, lq = lane >> 4;
    const int m0 = wave * 16;
    bf16x8 af[4];
#pragma unroll
    for (int kt = 0; kt < 4; ++kt)
        af[kt] = *reinterpret_cast<const bf16x8*>(&fA[(m0 + la) * 136 + kt * 32 + lq * 8]);
#pragma unroll
    for (int nt = 0; nt < 4; ++nt) {
        f32x4 acc = {0.f, 0.f, 0.f, 0.f};
#pragma unroll
        for (int kt = 0; kt < 4; ++kt) {
            bf16x8 bfr = *reinterpret_cast<const bf16x8*>(&fB[(nt * 16 + la) * 136 + kt * 32 + lq * 8]);
            acc = __builtin_amdgcn_mfma_f32_16x16x32_bf16(af[kt], bfr, acc, 0, 0, 0);
        }
#pragma unroll
        for (int r = 0; r < 4; ++r) {
            int m = m0 + lq * 4 + r;     // hw
            int nn = nt * 16 + la;       // ij
            if (m < 49 && nn < 49) Xrow[m * 49 + nn] = f2b(acc[r]);
        }
    }
}

// ---------------------------------------------------------------------------
// gemm1 body: H = gelu(X @ W1 + b1). M=CH, N=384, K=2432.
// BM=64, BN=128, BK=32. local grid (M/64)*3. 4 waves 2x2, wave tile 32x64.
// ---------------------------------------------------------------------------
__device__ __forceinline__ void gemm1_body(unsigned short* sm, int lb,
    const unsigned short* __restrict__ X,    // [M, 2432] bf16
    const unsigned short* __restrict__ W1T,  // [384, 2432] bf16
    const float* __restrict__ b1,            // [384] fp32
    unsigned short* __restrict__ Hout)       // [M, 384] bf16
{
    unsigned short* Al = sm;             // 64*40
    unsigned short* Bl = sm + 64 * 40;   // 128*40
    const int tid = threadIdx.x;
    const int bm = lb / 3, bn = lb - bm * 3;
    const int m_base = bm * 64, n_base = bn * 128;

    const int wave = tid >> 6, lane = tid & 63;
    const int wm = wave >> 1, wn = wave & 1;
    const int la = lane & 15, lq = lane >> 4;

    f32x4 acc[2][4];
#pragma unroll
    for (int i = 0; i < 2; ++i)
#pragma unroll
        for (int j = 0; j < 4; ++j) acc[i][j] = {0.f, 0.f, 0.f, 0.f};

    const int a_row = tid >> 2, a_c8 = (tid & 3) * 8;
    for (int k0 = 0; k0 < KPAD; k0 += 32) {
        {   // stage A: 64 rows x 32 k
            uint4 v = *reinterpret_cast<const uint4*>(
                X + (size_t)(m_base + a_row) * KPAD + k0 + a_c8);
            *reinterpret_cast<uint4*>(&Al[a_row * 40 + a_c8]) = v;
        }
#pragma unroll
        for (int i = 0; i < 2; ++i) {  // stage B: 128 rows x 32 k
            int idx = tid + i * 256;
            int row = idx >> 2, c8 = (idx & 3) * 8;
            uint4 v = *reinterpret_cast<const uint4*>(
                W1T + (size_t)(n_base + row) * KPAD + k0 + c8);
            *reinterpret_cast<uint4*>(&Bl[row * 40 + c8]) = v;
        }
        __syncthreads();
        bf16x8 af[2], bfr[4];
#pragma unroll
        for (int mt = 0; mt < 2; ++mt)
            af[mt] = *reinterpret_cast<const bf16x8*>(&Al[(wm * 32 + mt * 16 + la) * 40 + lq * 8]);
#pragma unroll
        for (int nt = 0; nt < 4; ++nt)
            bfr[nt] = *reinterpret_cast<const bf16x8*>(&Bl[(wn * 64 + nt * 16 + la) * 40 + lq * 8]);
#pragma unroll
        for (int mt = 0; mt < 2; ++mt)
#pragma unroll
            for (int nt = 0; nt < 4; ++nt)
                acc[mt][nt] = __builtin_amdgcn_mfma_f32_16x16x32_bf16(af[mt], bfr[nt], acc[mt][nt], 0, 0, 0);
        __syncthreads();
    }
#pragma unroll
    for (int mt = 0; mt < 2; ++mt) {
#pragma unroll
        for (int nt = 0; nt < 4; ++nt) {
            int nn = n_base + wn * 64 + nt * 16 + la;
            float bias = b1[nn];
#pragma unroll
            for (int r = 0; r < 4; ++r) {
                int m = m_base + wm * 32 + mt * 16 + lq * 4 + r;
                float v = acc[mt][nt][r] + bias;
                v = 0.5f * v * (1.0f + erff(v * 0.70710678118654752f));  // exact GELU
                Hout[(size_t)m * 384 + nn] = f2b(v);
            }
        }
    }
}

// ---------------------------------------------------------------------------
// gemm2 body: out[n0+m, lvl*256 + nn] = H @ W2 + b2 (fp32 out).
// M=CH, N=256, K=384. BM=64, BN=128. local grid (M/64)*2.
// ---------------------------------------------------------------------------
__device__ __forceinline__ void gemm2_body(unsigned short* sm, int lb,
    const unsigned short* __restrict__ Hin,  // [M, 384] bf16
    const unsigned short* __restrict__ W2T,  // [256, 384] bf16
    const float* __restrict__ b2,            // [256] fp32
    float* __restrict__ out,                 // [4096, 1024] fp32
    int lvl, int n0)
{
    unsigned short* Al = sm;             // 64*40
    unsigned short* Bl = sm + 64 * 40;   // 128*40
    const int tid = threadIdx.x;
    const int bm = lb >> 1, bn = lb & 1;
    const int m_base = bm * 64, n_base = bn * 128;

    const int wave = tid >> 6, lane = tid & 63;
    const int wm = wave >> 1, wn = wave & 1;
    const int la = lane & 15, lq = lane >> 4;

    f32x4 acc[2][4];
#pragma unroll
    for (int i = 0; i < 2; ++i)
#pragma unroll
        for (int j = 0; j < 4; ++j) acc[i][j] = {0.f, 0.f, 0.f, 0.f};

    const int a_row = tid >> 2, a_c8 = (tid & 3) * 8;
    for (int k0 = 0; k0 < 384; k0 += 32) {
        {
            uint4 v = *reinterpret_cast<const uint4*>(
                Hin + (size_t)(m_base + a_row) * 384 + k0 + a_c8);
            *reinterpret_cast<uint4*>(&Al[a_row * 40 + a_c8]) = v;
        }
#pragma unroll
        for (int i = 0; i < 2; ++i) {
            int idx = tid + i * 256;
            int row = idx >> 2, c8 = (idx & 3) * 8;
            uint4 v = *reinterpret_cast<const uint4*>(
                W2T + (size_t)(n_base + row) * 384 + k0 + c8);
            *reinterpret_cast<uint4*>(&Bl[row * 40 + c8]) = v;
        }
        __syncthreads();
        bf16x8 af[2], bfr[4];
#pragma unroll
        for (int mt = 0; mt < 2; ++mt)
            af[mt] = *reinterpret_cast<const bf16x8*>(&Al[(wm * 32 + mt * 16 + la) * 40 + lq * 8]);
#pragma unroll
        for (int nt = 0; nt < 4; ++nt)
            bfr[nt] = *reinterpret_cast<const bf16x8*>(&Bl[(wn * 64 + nt * 16 + la) * 40 + lq * 8]);
#pragma unroll
        for (int mt = 0; mt < 2; ++mt)
#pragma unroll
            for (int nt = 0; nt < 4; ++nt)
                acc[mt][nt] = __builtin_amdgcn_mfma_f32_16x16x32_bf16(af[mt], bfr[nt], acc[mt][nt], 0, 0, 0);
        __syncthreads();
    }
#pragma unroll
    for (int mt = 0; mt < 2; ++mt) {
#pragma unroll
        for (int nt = 0; nt < 4; ++nt) {
            int nn = n_base + wn * 64 + nt * 16 + la;
            float bias = b2[nn];
#pragma unroll
            for (int r = 0; r < 4; ++r) {
                int m = m_base + wm * 32 + mt * 16 + lq * 4 + r;
                out[(size_t)(n0 + m) * 1024 + lvl * 256 + nn] = acc[mt][nt][r] + bias;
            }
        }
    }
}

// ---------------------------------------------------------------------------
// Fused heterogeneous stage kernel: blocks [0,nCorr) -> corr(stage t),
// [nCorr,nCorr+nG1) -> gemm1(stage t-1), rest -> gemm2(stage t-2).
// Shared-mem union: corr needs 2*64*136 shorts (34,816 B), gemms 7,680 shorts.
// ---------------------------------------------------------------------------
__global__ __launch_bounds__(256) void k_stage(
    const unsigned short* __restrict__ fm, const float* __restrict__ tfp,
    const float* __restrict__ coords,
    unsigned short* __restrict__ Xd, int W, int H, float scale, int n0c, int nCorr,
    const unsigned short* __restrict__ Xs, const unsigned short* __restrict__ W1T,
    const float* __restrict__ b1, unsigned short* __restrict__ Hd, int nG1,
    const unsigned short* __restrict__ Hs, const unsigned short* __restrict__ W2T,
    const float* __restrict__ b2, float* __restrict__ out, int lvl2, int n0g2)
{
    __shared__ __align__(16) unsigned short sm[2 * 64 * 136];
    const int bb = blockIdx.x;
    if (bb < nCorr) {
        corr_body(sm, bb, fm, tfp, coords, Xd, W, H, scale, n0c);
    } else if (bb < nCorr + nG1) {
        gemm1_body(sm, bb - nCorr, Xs, W1T, b1, Hd);
    } else {
        gemm2_body(sm, bb - nCorr - nG1, Hs, W2T, b2, out, lvl2, n0g2);
    }
}

// ---------------------------------------------------------------------------
extern "C" void kernel_launch(void* const* d_in, const int* in_sizes, int n_in,
                              void* d_out, int out_size, void* d_ws, size_t ws_size,
                              hipStream_t stream)
{
    const float *fm[4], *tf[4], *coords, *w1, *b1, *w2, *b2;
    if (n_in >= 13 && in_sizes[0] == 384) {
        // alphabetical: b1,b2,coords,fmaps0-3,tfeat0-3,w1,w2
        b1 = (const float*)d_in[0]; b2 = (const float*)d_in[1];
        coords = (const float*)d_in[2];
        for (int i = 0; i < 4; ++i) fm[i] = (const float*)d_in[3 + i];
        for (int i = 0; i < 4; ++i) tf[i] = (const float*)d_in[7 + i];
        w1 = (const float*)d_in[11]; w2 = (const float*)d_in[12];
    } else if (n_in >= 13 && in_sizes[1] == 25690112) {
        // setup_inputs dict order: fmaps0,tfeat0,...,coords,w1,b1,w2,b2
        for (int i = 0; i < 4; ++i) { fm[i] = (const float*)d_in[2 * i];
                                      tf[i] = (const float*)d_in[2 * i + 1]; }
        coords = (const float*)d_in[8];
        w1 = (const float*)d_in[9];  b1 = (const float*)d_in[10];
        w2 = (const float*)d_in[11]; b2 = (const float*)d_in[12];
    } else {
        // reference-arg order: fmaps0-3, coords, tfeat0-3, w1, b1, w2, b2
        for (int i = 0; i < 4; ++i) fm[i] = (const float*)d_in[i];
        coords = (const float*)d_in[4];
        for (int i = 0; i < 4; ++i) tf[i] = (const float*)d_in[5 + i];
        w1 = (const float*)d_in[9];  b1 = (const float*)d_in[10];
        w2 = (const float*)d_in[11]; b2 = (const float*)d_in[12];
    }

    const int   cW[4]   = {128, 64, 32, 16};
    const int   cH[4]   = {96, 48, 24, 12};
    const int   cOff[4] = {0, 1572864, 1966080, 2064384};
    const float cS[4]   = {1.0f, 0.5f, 0.25f, 0.125f};

    // ---- workspace-adaptive layout --------------------------------------
    // needA (CH=4096, dbuf): 2*19,922,944 + 2*3,145,728 + 4,177,920
    //                        + 1,867,776 + 196,608 = 52,379,648
    // needB (CH=1024, dbuf): 2*4,980,736 + 2*786,432 + 6,242,304 = 17,776,640
    int CH, nbuf;
    if (ws_size >= (size_t)52379648)      { CH = 4096; nbuf = 2; }
    else if (ws_size >= (size_t)17776640) { CH = 1024; nbuf = 2; }
    else                                  { CH = 1024; nbuf = 1; }

    char* ws = (char*)d_ws;
    size_t xBytes = (size_t)CH * KPAD * 2;
    size_t hBytes = (size_t)CH * 384 * 2;
    size_t off = 0;
    unsigned short* Xb[2]; unsigned short* Hb[2];
    Xb[0] = (unsigned short*)(ws + off); off += xBytes;
    if (nbuf == 2) { Xb[1] = (unsigned short*)(ws + off); off += xBytes; }
    else           { Xb[1] = Xb[0]; }
    Hb[0] = (unsigned short*)(ws + off); off += hBytes;
    if (nbuf == 2) { Hb[1] = (unsigned short*)(ws + off); off += hBytes; }
    else           { Hb[1] = Hb[0]; }
    unsigned short* fmapT = (unsigned short*)(ws + off); off += 4177920;
    unsigned short* W1T   = (unsigned short*)(ws + off); off += 1867776;
    unsigned short* W2T   = (unsigned short*)(ws + off); off += 196608;

    hipLaunchKernelGGL(k_prep, dim3(12192), dim3(256), 0, stream,
                       fm[0], fm[1], fm[2], fm[3], w1, w2, fmapT, W1T, W2T);

    const int S   = (CH == 4096) ? 4 : 16;     // number of (level,chunk) stages
    const int nG1 = (CH / 64) * 3;             // gemm1 blocks per stage
    const int nG2 = (CH / 64) * 2;             // gemm2 blocks per stage

    if (nbuf == 2) {
        // Pipelined: launch t = corr(t) || gemm1(t-1) || gemm2(t-2).
        // Buffer parity by stage index; writer/reader of same buffer are
        // always >= 2 launches apart -> stream order guarantees safety.
        for (int t = 0; t < S + 2; ++t) {
            const int s0 = t, s1 = t - 1, s2 = t - 2;
            const int nc = (s0 < S) ? CH : 0;
            const int n1 = (s1 >= 0 && s1 < S) ? nG1 : 0;
            const int n2 = (s2 >= 0 && s2 < S) ? nG2 : 0;
            const int l0 = nc ? ((CH == 4096) ? s0 : (s0 >> 2)) : 0;
            const int l2 = n2 ? ((CH == 4096) ? s2 : (s2 >> 2)) : 0;
            const int n00 = (nc && CH != 4096) ? ((s0 & 3) << 10) : 0;
            const int n02 = (n2 && CH != 4096) ? ((s2 & 3) << 10) : 0;
            hipLaunchKernelGGL(k_stage, dim3(nc + n1 + n2), dim3(256), 0, stream,
                fmapT + cOff[l0], tf[l0], coords,
                Xb[t & 1], cW[l0], cH[l0], cS[l0], n00, nc,
                Xb[(t + 1) & 1], W1T, b1, Hb[(t + 1) & 1], n1,
                Hb[t & 1], W2T, b2, (float*)d_out, l2, n02);
        }
    } else {
        // Sequential fallback (single X/H buffers).
        for (int s = 0; s < S; ++s) {
            const int l = s >> 2, n0 = (s & 3) << 10;
            hipLaunchKernelGGL(k_stage, dim3(CH), dim3(256), 0, stream,
                fmapT + cOff[l], tf[l], coords,
                Xb[0], cW[l], cH[l], cS[l], n0, CH,
                Xb[0], W1T, b1, Hb[0], 0,
                Hb[0], W2T, b2, (float*)d_out, l, n0);
            hipLaunchKernelGGL(k_stage, dim3(nG1), dim3(256), 0, stream,
                fmapT, tf[0], coords, Xb[0], 0, 0, 0.f, 0, 0,
                Xb[0], W1T, b1, Hb[0], nG1,
                Hb[0], W2T, b2, (float*)d_out, l, n0);
            hipLaunchKernelGGL(k_stage, dim3(nG2), dim3(256), 0, stream,
                fmapT, tf[0], coords, Xb[0], 0, 0, 0.f, 0, 0,
                Xb[0], W1T, b1, Hb[0], 0,
                Hb[0], W2T, b2, (float*)d_out, l, n0);
        }
    }
}

// Round 2
// 661.273 us; speedup vs baseline: 1.9953x; 1.0624x over previous
//
#include <hip/hip_runtime.h>

// ---------------------------------------------------------------------------
// LiteTracker correlation-pyramid hot path. FP32 in/out, bf16 internal staging.
// Pipelined fused-stage schedule: launch t runs corr(t) || gemm1(t-1) ||
// gemm2(t-2) in one heterogeneous grid with double-buffered X / H.
// corr: deep-pipelined tf staging (fp32 in LDS, XOR-swizzled), per-wave
// bilinear gather, no zero-padding (garbage rows feed discarded outputs).
// ---------------------------------------------------------------------------

typedef __bf16 bf16x8 __attribute__((ext_vector_type(8)));
typedef float f32x4 __attribute__((ext_vector_type(4)));

#define KPAD 2432          // 2401 padded to 76*32
#define K_RAW 2401
#define NPTS 4096

// shared-memory layout for corr (bytes):
//   fA  bf16 [49][136]  @ 0       : 13,328 B  (reads up to row 63 spill into fB: harmless)
//   fBf fp32 [49][128]  @ 13,328  : 25,088 B  (XOR-swizzled: byte ^= ((row&7)<<4))
#define FB_BYTE   13328
#define SM_SHORTS 19208            // 38,416 B total -> 4 blocks/CU

__device__ __forceinline__ float b2f(unsigned short u) {
    return __uint_as_float(((unsigned int)u) << 16);
}
__device__ __forceinline__ unsigned short f2b(float f) {
    unsigned int u = __float_as_uint(f);
    u += 0x7fffu + ((u >> 16) & 1u);   // round-to-nearest-even
    return (unsigned short)(u >> 16);
}
__device__ __forceinline__ void unpack8(uint4 v, float* f) {
    f[0] = b2f((unsigned short)(v.x & 0xffffu)); f[1] = b2f((unsigned short)(v.x >> 16));
    f[2] = b2f((unsigned short)(v.y & 0xffffu)); f[3] = b2f((unsigned short)(v.y >> 16));
    f[4] = b2f((unsigned short)(v.z & 0xffffu)); f[5] = b2f((unsigned short)(v.z >> 16));
    f[6] = b2f((unsigned short)(v.w & 0xffffu)); f[7] = b2f((unsigned short)(v.w >> 16));
}

// ---------------------------------------------------------------------------
// k_prep. Region A: fmap transpose, source-linear. Regions B/C: weight
// transposes, dest-linear. total elems 3,121,152 -> grid 12192 x 256
// ---------------------------------------------------------------------------
__global__ __launch_bounds__(256) void k_prep(
    const float* __restrict__ f0, const float* __restrict__ f1,
    const float* __restrict__ f2, const float* __restrict__ f3,
    const float* __restrict__ w1, const float* __restrict__ w2,
    unsigned short* __restrict__ fmapT, unsigned short* __restrict__ W1T,
    unsigned short* __restrict__ W2T)
{
    int idx = blockIdx.x * 256 + threadIdx.x;
    const int FT = 2088960;
    if (idx < FT) {
        int off, HW;
        const float* src;
        if (idx < 1572864)      { off = 0;       HW = 12288; src = f0; }
        else if (idx < 1966080) { off = 1572864; HW = 3072;  src = f1; }
        else if (idx < 2064384) { off = 1966080; HW = 768;   src = f2; }
        else                    { off = 2064384; HW = 192;   src = f3; }
        int r = idx - off;
        int c = r / HW, p = r - c * HW;          // src layout [128][HW]
        fmapT[off + p * 128 + c] = f2b(src[r]);  // dst layout [HW][128]
    } else if (idx < FT + 933888) {
        int j = idx - FT;
        int n = j / KPAD, k = j - n * KPAD;
        W1T[j] = (k < K_RAW) ? f2b(w1[k * 384 + n]) : (unsigned short)0;
    } else if (idx < FT + 933888 + 98304) {
        int j = idx - (FT + 933888);
        int n = j / 384, k = j - n * 384;
        W2T[j] = f2b(w2[k * 256 + n]);
    }
}

// ---------------------------------------------------------------------------
// corr body: one block (256 thr, 4 waves) per point.
// Phase 1: issue ~6.1 deep-pipelined 16B tf loads/thread (fp32, swizzled dest)
// Phase 2: per-wave bilinear gather (wave w owns fA rows [16w,16w+16))
// Phase 3: write fB, one barrier, MFMA with read-time bf16 conversion.
// ---------------------------------------------------------------------------
__device__ __forceinline__ void corr_body(unsigned short* sm, int bb,
    const unsigned short* __restrict__ fm,   // level's [H*W,128] bf16 fmapT
    const float* __restrict__ tf,            // level's tfeat fp32 [49,4096,128]
    const float* __restrict__ coords,        // fp32 [4096,2]
    unsigned short* __restrict__ X,          // [CH, 2432] bf16
    int W, int H, float scale, int n0)
{
    unsigned short* fA = sm;
    char* fB = (char*)sm + FB_BYTE;
    const int tid = threadIdx.x;
    const int lane = tid & 63, wave = tid >> 6;
    const int n = n0 + bb;

    const float px = coords[2 * n]     * scale;
    const float py = coords[2 * n + 1] * scale;
    const float* tfn = tf + (size_t)n * 128;

    // ---- phase 1: issue all tf stage loads (1568 16B chunks; 6-7/thread) ----
    uint4 rv[7];
#pragma unroll
    for (int k = 0; k < 7; ++k) {
        if (k < 6 || tid < 32) {
            int c = tid + (k << 8);
            int g = c >> 5;                    // tf support row 0..48
            int L = c << 4;                    // logical byte in [49][512B]
            rv[k] = *reinterpret_cast<const uint4*>(
                tfn + (size_t)g * (NPTS * 128) + ((L & 511) >> 2));
        }
    }

    // ---- phase 2: bilinear gather; wave w -> fA rows [16w, 16w+16) ----
    const int c8 = lane & 15;
    const int s_base = wave * 16 + (lane >> 4);
#pragma unroll
    for (int k = 0; k < 4; ++k) {
        int s = s_base + 4 * k;
        if (s < 49) {
            int a = s / 7, b = s - a * 7;
            float sx = px + (float)(a - 3);
            float sy = py + (float)(b - 3);
            float x0f = floorf(sx), y0f = floorf(sy);
            float wx = sx - x0f, wy = sy - y0f;
            int x0 = (int)x0f, y0 = (int)y0f;
            int x1 = x0 + 1, y1 = y0 + 1;
            int xc0 = x0 < 0 ? 0 : (x0 >= W ? W - 1 : x0);
            int xc1 = x1 < 0 ? 0 : (x1 >= W ? W - 1 : x1);
            int yc0 = y0 < 0 ? 0 : (y0 >= H ? H - 1 : y0);
            int yc1 = y1 < 0 ? 0 : (y1 >= H ? H - 1 : y1);
            float vx0 = (x0 >= 0 && x0 < W) ? 1.f : 0.f;
            float vx1 = (x1 >= 0 && x1 < W) ? 1.f : 0.f;
            float vy0 = (y0 >= 0 && y0 < H) ? 1.f : 0.f;
            float vy1 = (y1 >= 0 && y1 < H) ? 1.f : 0.f;
            float w00 = (1.f - wy) * (1.f - wx) * vy0 * vx0;
            float w01 = (1.f - wy) * wx         * vy0 * vx1;
            float w10 = wy         * (1.f - wx) * vy1 * vx0;
            float w11 = wy         * wx         * vy1 * vx1;
            const unsigned short* pb = fm + c8 * 8;
            uint4 q00 = *reinterpret_cast<const uint4*>(pb + (size_t)(yc0 * W + xc0) * 128);
            uint4 q01 = *reinterpret_cast<const uint4*>(pb + (size_t)(yc0 * W + xc1) * 128);
            uint4 q10 = *reinterpret_cast<const uint4*>(pb + (size_t)(yc1 * W + xc0) * 128);
            uint4 q11 = *reinterpret_cast<const uint4*>(pb + (size_t)(yc1 * W + xc1) * 128);
            float f00[8], f01[8], f10[8], f11[8];
            unpack8(q00, f00); unpack8(q01, f01); unpack8(q10, f10); unpack8(q11, f11);
            bf16x8 r;
#pragma unroll
            for (int j = 0; j < 8; ++j) {
                float v = w00 * f00[j] + w01 * f01[j] + w10 * f10[j] + w11 * f11[j];
                r[j] = (__bf16)v;
            }
            *reinterpret_cast<bf16x8*>(&fA[s * 136 + c8 * 8]) = r;
        }
    }

    unsigned short* Xrow = X + (size_t)bb * KPAD;
    if (tid < 31) Xrow[K_RAW + tid] = 0;   // zero K padding of X

    // ---- phase 3: land tf loads into swizzled fp32 LDS ----
#pragma unroll
    for (int k = 0; k < 7; ++k) {
        if (k < 6 || tid < 32) {
            int c = tid + (k << 8);
            int g = c >> 5;
            int L = c << 4;
            int po = L ^ ((g & 7) << 4);
            *reinterpret_cast<uint4*>(fB + po) = rv[k];
        }
    }
    __syncthreads();

    // ---- MFMA: wave w -> S rows [16w,16w+16); 4 col tiles; K=128 ----
    const int la = lane & 15, lq = lane >> 4;
    const int m0 = wave * 16;
    bf16x8 af[4];
#pragma unroll
    for (int kt = 0; kt < 4; ++kt)
        af[kt] = *reinterpret_cast<const bf16x8*>(&fA[(m0 + la) * 136 + kt * 32 + lq * 8]);
#pragma unroll
    for (int nt = 0; nt < 4; ++nt) {
        int row = nt * 16 + la;               // ij column of S
        int rowc = row < 49 ? row : 48;       // clamp: keep LDS reads in-bounds
        int rswz = (rowc & 7) << 4;
        f32x4 acc = {0.f, 0.f, 0.f, 0.f};
#pragma unroll
        for (int kt = 0; kt < 4; ++kt) {
            int Lb = rowc * 512 + kt * 128 + lq * 32;
            f32x4 h0 = *reinterpret_cast<const f32x4*>(fB + (Lb ^ rswz));
            f32x4 h1 = *reinterpret_cast<const f32x4*>(fB + ((Lb + 16) ^ rswz));
            bf16x8 bfr;
            bfr[0] = (__bf16)h0[0]; bfr[1] = (__bf16)h0[1];
            bfr[2] = (__bf16)h0[2]; bfr[3] = (__bf16)h0[3];
            bfr[4] = (__bf16)h1[0]; bfr[5] = (__bf16)h1[1];
            bfr[6] = (__bf16)h1[2]; bfr[7] = (__bf16)h1[3];
            acc = __builtin_amdgcn_mfma_f32_16x16x32_bf16(af[kt], bfr, acc, 0, 0, 0);
        }
#pragma unroll
        for (int r = 0; r < 4; ++r) {
            int m = m0 + lq * 4 + r;          // hw row of S
            if (m < 49 && row < 49) Xrow[m * 49 + row] = f2b(acc[r]);
        }
    }
}

// ---------------------------------------------------------------------------
// gemm1 body: H = gelu(X @ W1 + b1). M=CH, N=384, K=2432.
// BM=64, BN=128, BK=32. local grid (M/64)*3. 4 waves 2x2, wave tile 32x64.
// ---------------------------------------------------------------------------
__device__ __forceinline__ void gemm1_body(unsigned short* sm, int lb,
    const unsigned short* __restrict__ X,    // [M, 2432] bf16
    const unsigned short* __restrict__ W1T,  // [384, 2432] bf16
    const float* __restrict__ b1,            // [384] fp32
    unsigned short* __restrict__ Hout)       // [M, 384] bf16
{
    unsigned short* Al = sm;             // 64*40
    unsigned short* Bl = sm + 64 * 40;   // 128*40
    const int tid = threadIdx.x;
    const int bm = lb / 3, bn = lb - bm * 3;
    const int m_base = bm * 64, n_base = bn * 128;

    const int wave = tid >> 6, lane = tid & 63;
    const int wm = wave >> 1, wn = wave & 1;
    const int la = lane & 15, lq = lane >> 4;

    f32x4 acc[2][4];
#pragma unroll
    for (int i = 0; i < 2; ++i)
#pragma unroll
        for (int j = 0; j < 4; ++j) acc[i][j] = {0.f, 0.f, 0.f, 0.f};

    const int a_row = tid >> 2, a_c8 = (tid & 3) * 8;
    for (int k0 = 0; k0 < KPAD; k0 += 32) {
        {   // stage A: 64 rows x 32 k
            uint4 v = *reinterpret_cast<const uint4*>(
                X + (size_t)(m_base + a_row) * KPAD + k0 + a_c8);
            *reinterpret_cast<uint4*>(&Al[a_row * 40 + a_c8]) = v;
        }
#pragma unroll
        for (int i = 0; i < 2; ++i) {  // stage B: 128 rows x 32 k
            int idx = tid + i * 256;
            int row = idx >> 2, c8 = (idx & 3) * 8;
            uint4 v = *reinterpret_cast<const uint4*>(
                W1T + (size_t)(n_base + row) * KPAD + k0 + c8);
            *reinterpret_cast<uint4*>(&Bl[row * 40 + c8]) = v;
        }
        __syncthreads();
        bf16x8 af[2], bfr[4];
#pragma unroll
        for (int mt = 0; mt < 2; ++mt)
            af[mt] = *reinterpret_cast<const bf16x8*>(&Al[(wm * 32 + mt * 16 + la) * 40 + lq * 8]);
#pragma unroll
        for (int nt = 0; nt < 4; ++nt)
            bfr[nt] = *reinterpret_cast<const bf16x8*>(&Bl[(wn * 64 + nt * 16 + la) * 40 + lq * 8]);
#pragma unroll
        for (int mt = 0; mt < 2; ++mt)
#pragma unroll
            for (int nt = 0; nt < 4; ++nt)
                acc[mt][nt] = __builtin_amdgcn_mfma_f32_16x16x32_bf16(af[mt], bfr[nt], acc[mt][nt], 0, 0, 0);
        __syncthreads();
    }
#pragma unroll
    for (int mt = 0; mt < 2; ++mt) {
#pragma unroll
        for (int nt = 0; nt < 4; ++nt) {
            int nn = n_base + wn * 64 + nt * 16 + la;
            float bias = b1[nn];
#pragma unroll
            for (int r = 0; r < 4; ++r) {
                int m = m_base + wm * 32 + mt * 16 + lq * 4 + r;
                float v = acc[mt][nt][r] + bias;
                v = 0.5f * v * (1.0f + erff(v * 0.70710678118654752f));  // exact GELU
                Hout[(size_t)m * 384 + nn] = f2b(v);
            }
        }
    }
}

// ---------------------------------------------------------------------------
// gemm2 body: out[n0+m, lvl*256 + nn] = H @ W2 + b2 (fp32 out).
// M=CH, N=256, K=384. BM=64, BN=128. local grid (M/64)*2.
// ---------------------------------------------------------------------------
__device__ __forceinline__ void gemm2_body(unsigned short* sm, int lb,
    const unsigned short* __restrict__ Hin,  // [M, 384] bf16
    const unsigned short* __restrict__ W2T,  // [256, 384] bf16
    const float* __restrict__ b2,            // [256] fp32
    float* __restrict__ out,                 // [4096, 1024] fp32
    int lvl, int n0)
{
    unsigned short* Al = sm;             // 64*40
    unsigned short* Bl = sm + 64 * 40;   // 128*40
    const int tid = threadIdx.x;
    const int bm = lb >> 1, bn = lb & 1;
    const int m_base = bm * 64, n_base = bn * 128;

    const int wave = tid >> 6, lane = tid & 63;
    const int wm = wave >> 1, wn = wave & 1;
    const int la = lane & 15, lq = lane >> 4;

    f32x4 acc[2][4];
#pragma unroll
    for (int i = 0; i < 2; ++i)
#pragma unroll
        for (int j = 0; j < 4; ++j) acc[i][j] = {0.f, 0.f, 0.f, 0.f};

    const int a_row = tid >> 2, a_c8 = (tid & 3) * 8;
    for (int k0 = 0; k0 < 384; k0 += 32) {
        {
            uint4 v = *reinterpret_cast<const uint4*>(
                Hin + (size_t)(m_base + a_row) * 384 + k0 + a_c8);
            *reinterpret_cast<uint4*>(&Al[a_row * 40 + a_c8]) = v;
        }
#pragma unroll
        for (int i = 0; i < 2; ++i) {
            int idx = tid + i * 256;
            int row = idx >> 2, c8 = (idx & 3) * 8;
            uint4 v = *reinterpret_cast<const uint4*>(
                W2T + (size_t)(n_base + row) * 384 + k0 + c8);
            *reinterpret_cast<uint4*>(&Bl[row * 40 + c8]) = v;
        }
        __syncthreads();
        bf16x8 af[2], bfr[4];
#pragma unroll
        for (int mt = 0; mt < 2; ++mt)
            af[mt] = *reinterpret_cast<const bf16x8*>(&Al[(wm * 32 + mt * 16 + la) * 40 + lq * 8]);
#pragma unroll
        for (int nt = 0; nt < 4; ++nt)
            bfr[nt] = *reinterpret_cast<const bf16x8*>(&Bl[(wn * 64 + nt * 16 + la) * 40 + lq * 8]);
#pragma unroll
        for (int mt = 0; mt < 2; ++mt)
#pragma unroll
            for (int nt = 0; nt < 4; ++nt)
                acc[mt][nt] = __builtin_amdgcn_mfma_f32_16x16x32_bf16(af[mt], bfr[nt], acc[mt][nt], 0, 0, 0);
        __syncthreads();
    }
#pragma unroll
    for (int mt = 0; mt < 2; ++mt) {
#pragma unroll
        for (int nt = 0; nt < 4; ++nt) {
            int nn = n_base + wn * 64 + nt * 16 + la;
            float bias = b2[nn];
#pragma unroll
            for (int r = 0; r < 4; ++r) {
                int m = m_base + wm * 32 + mt * 16 + lq * 4 + r;
                out[(size_t)(n0 + m) * 1024 + lvl * 256 + nn] = acc[mt][nt][r] + bias;
            }
        }
    }
}

// ---------------------------------------------------------------------------
// Fused heterogeneous stage kernel. Gemm blocks dispatch FIRST so the
// previous stage's gemms start immediately, then the corr flood.
// blocks [0,nG1) -> gemm1(t-1); [nG1,nG1+nG2) -> gemm2(t-2); rest -> corr(t).
// ---------------------------------------------------------------------------
__global__ __launch_bounds__(256, 4) void k_stage(
    const unsigned short* __restrict__ fm, const float* __restrict__ tfp,
    const float* __restrict__ coords,
    unsigned short* __restrict__ Xd, int W, int H, float scale, int n0c,
    const unsigned short* __restrict__ Xs, const unsigned short* __restrict__ W1T,
    const float* __restrict__ b1, unsigned short* __restrict__ Hd, int nG1,
    const unsigned short* __restrict__ Hs, const unsigned short* __restrict__ W2T,
    const float* __restrict__ b2, float* __restrict__ out, int lvl2, int n0g2,
    int nG2)
{
    __shared__ __align__(16) unsigned short sm[SM_SHORTS];
    const int bb = blockIdx.x;
    if (bb < nG1) {
        gemm1_body(sm, bb, Xs, W1T, b1, Hd);
    } else if (bb < nG1 + nG2) {
        gemm2_body(sm, bb - nG1, Hs, W2T, b2, out, lvl2, n0g2);
    } else {
        corr_body(sm, bb - nG1 - nG2, fm, tfp, coords, Xd, W, H, scale, n0c);
    }
}

// ---------------------------------------------------------------------------
extern "C" void kernel_launch(void* const* d_in, const int* in_sizes, int n_in,
                              void* d_out, int out_size, void* d_ws, size_t ws_size,
                              hipStream_t stream)
{
    const float *fm[4], *tf[4], *coords, *w1, *b1, *w2, *b2;
    if (n_in >= 13 && in_sizes[0] == 384) {
        // alphabetical: b1,b2,coords,fmaps0-3,tfeat0-3,w1,w2
        b1 = (const float*)d_in[0]; b2 = (const float*)d_in[1];
        coords = (const float*)d_in[2];
        for (int i = 0; i < 4; ++i) fm[i] = (const float*)d_in[3 + i];
        for (int i = 0; i < 4; ++i) tf[i] = (const float*)d_in[7 + i];
        w1 = (const float*)d_in[11]; w2 = (const float*)d_in[12];
    } else if (n_in >= 13 && in_sizes[1] == 25690112) {
        // setup_inputs dict order: fmaps0,tfeat0,...,coords,w1,b1,w2,b2
        for (int i = 0; i < 4; ++i) { fm[i] = (const float*)d_in[2 * i];
                                      tf[i] = (const float*)d_in[2 * i + 1]; }
        coords = (const float*)d_in[8];
        w1 = (const float*)d_in[9];  b1 = (const float*)d_in[10];
        w2 = (const float*)d_in[11]; b2 = (const float*)d_in[12];
    } else {
        // reference-arg order: fmaps0-3, coords, tfeat0-3, w1, b1, w2, b2
        for (int i = 0; i < 4; ++i) fm[i] = (const float*)d_in[i];
        coords = (const float*)d_in[4];
        for (int i = 0; i < 4; ++i) tf[i] = (const float*)d_in[5 + i];
        w1 = (const float*)d_in[9];  b1 = (const float*)d_in[10];
        w2 = (const float*)d_in[11]; b2 = (const float*)d_in[12];
    }

    const int   cW[4]   = {128, 64, 32, 16};
    const int   cH[4]   = {96, 48, 24, 12};
    const int   cOff[4] = {0, 1572864, 1966080, 2064384};
    const float cS[4]   = {1.0f, 0.5f, 0.25f, 0.125f};

    // ---- workspace-adaptive layout --------------------------------------
    int CH, nbuf;
    if (ws_size >= (size_t)52379648)      { CH = 4096; nbuf = 2; }
    else if (ws_size >= (size_t)17776640) { CH = 1024; nbuf = 2; }
    else                                  { CH = 1024; nbuf = 1; }

    char* ws = (char*)d_ws;
    size_t xBytes = (size_t)CH * KPAD * 2;
    size_t hBytes = (size_t)CH * 384 * 2;
    size_t off = 0;
    unsigned short* Xb[2]; unsigned short* Hb[2];
    Xb[0] = (unsigned short*)(ws + off); off += xBytes;
    if (nbuf == 2) { Xb[1] = (unsigned short*)(ws + off); off += xBytes; }
    else           { Xb[1] = Xb[0]; }
    Hb[0] = (unsigned short*)(ws + off); off += hBytes;
    if (nbuf == 2) { Hb[1] = (unsigned short*)(ws + off); off += hBytes; }
    else           { Hb[1] = Hb[0]; }
    unsigned short* fmapT = (unsigned short*)(ws + off); off += 4177920;
    unsigned short* W1T   = (unsigned short*)(ws + off); off += 1867776;
    unsigned short* W2T   = (unsigned short*)(ws + off); off += 196608;

    hipLaunchKernelGGL(k_prep, dim3(12192), dim3(256), 0, stream,
                       fm[0], fm[1], fm[2], fm[3], w1, w2, fmapT, W1T, W2T);

    const int S   = (CH == 4096) ? 4 : 16;     // number of (level,chunk) stages
    const int nG1 = (CH / 64) * 3;             // gemm1 blocks per stage
    const int nG2 = (CH / 64) * 2;             // gemm2 blocks per stage

    if (nbuf == 2) {
        // Pipelined: launch t = corr(t) || gemm1(t-1) || gemm2(t-2).
        for (int t = 0; t < S + 2; ++t) {
            const int s0 = t, s1 = t - 1, s2 = t - 2;
            const int nc = (s0 < S) ? CH : 0;
            const int n1 = (s1 >= 0 && s1 < S) ? nG1 : 0;
            const int n2 = (s2 >= 0 && s2 < S) ? nG2 : 0;
            const int l0 = nc ? ((CH == 4096) ? s0 : (s0 >> 2)) : 0;
            const int l2 = n2 ? ((CH == 4096) ? s2 : (s2 >> 2)) : 0;
            const int n00 = (nc && CH != 4096) ? ((s0 & 3) << 10) : 0;
            const int n02 = (n2 && CH != 4096) ? ((s2 & 3) << 10) : 0;
            hipLaunchKernelGGL(k_stage, dim3(nc + n1 + n2), dim3(256), 0, stream,
                fmapT + cOff[l0], tf[l0], coords,
                Xb[t & 1], cW[l0], cH[l0], cS[l0], n00,
                Xb[(t + 1) & 1], W1T, b1, Hb[(t + 1) & 1], n1,
                Hb[t & 1], W2T, b2, (float*)d_out, l2, n02, n2);
        }
    } else {
        // Sequential fallback (single X/H buffers).
        for (int s = 0; s < S; ++s) {
            const int l = s >> 2, n0 = (s & 3) << 10;
            hipLaunchKernelGGL(k_stage, dim3(CH), dim3(256), 0, stream,
                fmapT + cOff[l], tf[l], coords,
                Xb[0], cW[l], cH[l], cS[l], n0,
                Xb[0], W1T, b1, Hb[0], 0,
                Hb[0], W2T, b2, (float*)d_out, l, n0, 0);
            hipLaunchKernelGGL(k_stage, dim3(nG1), dim3(256), 0, stream,
                fmapT, tf[0], coords, Xb[0], 0, 0, 0.f, 0,
                Xb[0], W1T, b1, Hb[0], nG1,
                Hb[0], W2T, b2, (float*)d_out, l, n0, 0);
            hipLaunchKernelGGL(k_stage, dim3(nG2), dim3(256), 0, stream,
                fmapT, tf[0], coords, Xb[0], 0, 0, 0.f, 0,
                Xb[0], W1T, b1, Hb[0], 0,
                Hb[0], W2T, b2, (float*)d_out, l, n0, nG2);
        }
    }
}

// Round 4
// 657.842 us; speedup vs baseline: 2.0057x; 1.0052x over previous
//
#include <hip/hip_runtime.h>

// ---------------------------------------------------------------------------
// LiteTracker correlation-pyramid hot path. FP32 in/out, bf16 internal staging.
// Pipelined fused-stage schedule: launch t runs corr(t) || gemm1(t-1) ||
// gemm2(t-2) in one heterogeneous grid with double-buffered X / H.
// corr: deep-pipelined tf staging (fp32 in LDS, XOR-swizzled), per-wave
// bilinear gather. gemm1/gemm2: LDS double-buffered K-loop with register
// prefetch issued AFTER the barrier (avoids the vmcnt(0)-drain-at-barrier
// stall), one barrier per iteration.
// ---------------------------------------------------------------------------

typedef __bf16 bf16x8 __attribute__((ext_vector_type(8)));
typedef float f32x4 __attribute__((ext_vector_type(4)));

#define KPAD 2432          // 2401 padded to 76*32
#define K_RAW 2401
#define NPTS 4096

// shared-memory layout for corr (bytes):
//   fA  bf16 [49][136]  @ 0       : 13,328 B  (reads up to row 63 spill into fB: harmless)
//   fBf fp32 [49][128]  @ 13,328  : 25,088 B  (XOR-swizzled: byte ^= ((row&7)<<4))
// gemm double-buffer: 2 x (A 64*40 + B 128*40) shorts = 30,720 B  (fits)
#define FB_BYTE   13328
#define SM_SHORTS 19208            // 38,416 B total -> 4 blocks/CU

__device__ __forceinline__ float b2f(unsigned short u) {
    return __uint_as_float(((unsigned int)u) << 16);
}
__device__ __forceinline__ unsigned short f2b(float f) {
    unsigned int u = __float_as_uint(f);
    u += 0x7fffu + ((u >> 16) & 1u);   // round-to-nearest-even
    return (unsigned short)(u >> 16);
}
__device__ __forceinline__ void unpack8(uint4 v, float* f) {
    f[0] = b2f((unsigned short)(v.x & 0xffffu)); f[1] = b2f((unsigned short)(v.x >> 16));
    f[2] = b2f((unsigned short)(v.y & 0xffffu)); f[3] = b2f((unsigned short)(v.y >> 16));
    f[4] = b2f((unsigned short)(v.z & 0xffffu)); f[5] = b2f((unsigned short)(v.z >> 16));
    f[6] = b2f((unsigned short)(v.w & 0xffffu)); f[7] = b2f((unsigned short)(v.w >> 16));
}

// ---------------------------------------------------------------------------
// k_prep. Region A: fmap transpose, source-linear. Regions B/C: weight
// transposes, dest-linear. total elems 3,121,152 -> grid 12192 x 256
// ---------------------------------------------------------------------------
__global__ __launch_bounds__(256) void k_prep(
    const float* __restrict__ f0, const float* __restrict__ f1,
    const float* __restrict__ f2, const float* __restrict__ f3,
    const float* __restrict__ w1, const float* __restrict__ w2,
    unsigned short* __restrict__ fmapT, unsigned short* __restrict__ W1T,
    unsigned short* __restrict__ W2T)
{
    int idx = blockIdx.x * 256 + threadIdx.x;
    const int FT = 2088960;
    if (idx < FT) {
        int off, HW;
        const float* src;
        if (idx < 1572864)      { off = 0;       HW = 12288; src = f0; }
        else if (idx < 1966080) { off = 1572864; HW = 3072;  src = f1; }
        else if (idx < 2064384) { off = 1966080; HW = 768;   src = f2; }
        else                    { off = 2064384; HW = 192;   src = f3; }
        int r = idx - off;
        int c = r / HW, p = r - c * HW;          // src layout [128][HW]
        fmapT[off + p * 128 + c] = f2b(src[r]);  // dst layout [HW][128]
    } else if (idx < FT + 933888) {
        int j = idx - FT;
        int n = j / KPAD, k = j - n * KPAD;
        W1T[j] = (k < K_RAW) ? f2b(w1[k * 384 + n]) : (unsigned short)0;
    } else if (idx < FT + 933888 + 98304) {
        int j = idx - (FT + 933888);
        int n = j / 384, k = j - n * 384;
        W2T[j] = f2b(w2[k * 256 + n]);
    }
}

// ---------------------------------------------------------------------------
// corr body: one block (256 thr, 4 waves) per point.
// Phase 1: issue ~6.1 deep-pipelined 16B tf loads/thread (fp32, swizzled dest)
// Phase 2: per-wave bilinear gather (wave w owns fA rows [16w,16w+16))
// Phase 3: write fB, one barrier, MFMA with read-time bf16 conversion.
// ---------------------------------------------------------------------------
__device__ __forceinline__ void corr_body(unsigned short* sm, int bb,
    const unsigned short* __restrict__ fm,   // level's [H*W,128] bf16 fmapT
    const float* __restrict__ tf,            // level's tfeat fp32 [49,4096,128]
    const float* __restrict__ coords,        // fp32 [4096,2]
    unsigned short* __restrict__ X,          // [CH, 2432] bf16
    int W, int H, float scale, int n0)
{
    unsigned short* fA = sm;
    char* fB = (char*)sm + FB_BYTE;
    const int tid = threadIdx.x;
    const int lane = tid & 63, wave = tid >> 6;
    const int n = n0 + bb;

    const float px = coords[2 * n]     * scale;
    const float py = coords[2 * n + 1] * scale;
    const float* tfn = tf + (size_t)n * 128;

    // ---- phase 1: issue all tf stage loads (1568 16B chunks; 6-7/thread) ----
    uint4 rv[7];
#pragma unroll
    for (int k = 0; k < 7; ++k) {
        if (k < 6 || tid < 32) {
            int c = tid + (k << 8);
            int g = c >> 5;                    // tf support row 0..48
            int L = c << 4;                    // logical byte in [49][512B]
            rv[k] = *reinterpret_cast<const uint4*>(
                tfn + (size_t)g * (NPTS * 128) + ((L & 511) >> 2));
        }
    }

    // ---- phase 2: bilinear gather; wave w -> fA rows [16w, 16w+16) ----
    const int c8 = lane & 15;
    const int s_base = wave * 16 + (lane >> 4);
#pragma unroll
    for (int k = 0; k < 4; ++k) {
        int s = s_base + 4 * k;
        if (s < 49) {
            int a = s / 7, b = s - a * 7;
            float sx = px + (float)(a - 3);
            float sy = py + (float)(b - 3);
            float x0f = floorf(sx), y0f = floorf(sy);
            float wx = sx - x0f, wy = sy - y0f;
            int x0 = (int)x0f, y0 = (int)y0f;
            int x1 = x0 + 1, y1 = y0 + 1;
            int xc0 = x0 < 0 ? 0 : (x0 >= W ? W - 1 : x0);
            int xc1 = x1 < 0 ? 0 : (x1 >= W ? W - 1 : x1);
            int yc0 = y0 < 0 ? 0 : (y0 >= H ? H - 1 : y0);
            int yc1 = y1 < 0 ? 0 : (y1 >= H ? H - 1 : y1);
            float vx0 = (x0 >= 0 && x0 < W) ? 1.f : 0.f;
            float vx1 = (x1 >= 0 && x1 < W) ? 1.f : 0.f;
            float vy0 = (y0 >= 0 && y0 < H) ? 1.f : 0.f;
            float vy1 = (y1 >= 0 && y1 < H) ? 1.f : 0.f;
            float w00 = (1.f - wy) * (1.f - wx) * vy0 * vx0;
            float w01 = (1.f - wy) * wx         * vy0 * vx1;
            float w10 = wy         * (1.f - wx) * vy1 * vx0;
            float w11 = wy         * wx         * vy1 * vx1;
            const unsigned short* pb = fm + c8 * 8;
            uint4 q00 = *reinterpret_cast<const uint4*>(pb + (size_t)(yc0 * W + xc0) * 128);
            uint4 q01 = *reinterpret_cast<const uint4*>(pb + (size_t)(yc0 * W + xc1) * 128);
            uint4 q10 = *reinterpret_cast<const uint4*>(pb + (size_t)(yc1 * W + xc0) * 128);
            uint4 q11 = *reinterpret_cast<const uint4*>(pb + (size_t)(yc1 * W + xc1) * 128);
            float f00[8], f01[8], f10[8], f11[8];
            unpack8(q00, f00); unpack8(q01, f01); unpack8(q10, f10); unpack8(q11, f11);
            bf16x8 r;
#pragma unroll
            for (int j = 0; j < 8; ++j) {
                float v = w00 * f00[j] + w01 * f01[j] + w10 * f10[j] + w11 * f11[j];
                r[j] = (__bf16)v;
            }
            *reinterpret_cast<bf16x8*>(&fA[s * 136 + c8 * 8]) = r;
        }
    }

    unsigned short* Xrow = X + (size_t)bb * KPAD;
    if (tid < 31) Xrow[K_RAW + tid] = 0;   // zero K padding of X

    // ---- phase 3: land tf loads into swizzled fp32 LDS ----
#pragma unroll
    for (int k = 0; k < 7; ++k) {
        if (k < 6 || tid < 32) {
            int c = tid + (k << 8);
            int g = c >> 5;
            int L = c << 4;
            int po = L ^ ((g & 7) << 4);
            *reinterpret_cast<uint4*>(fB + po) = rv[k];
        }
    }
    __syncthreads();

    // ---- MFMA: wave w -> S rows [16w,16w+16); 4 col tiles; K=128 ----
    const int la = lane & 15, lq = lane >> 4;
    const int m0 = wave * 16;
    bf16x8 af[4];
#pragma unroll
    for (int kt = 0; kt < 4; ++kt)
        af[kt] = *reinterpret_cast<const bf16x8*>(&fA[(m0 + la) * 136 + kt * 32 + lq * 8]);
#pragma unroll
    for (int nt = 0; nt < 4; ++nt) {
        int row = nt * 16 + la;               // ij column of S
        int rowc = row < 49 ? row : 48;       // clamp: keep LDS reads in-bounds
        int rswz = (rowc & 7) << 4;
        f32x4 acc = {0.f, 0.f, 0.f, 0.f};
#pragma unroll
        for (int kt = 0; kt < 4; ++kt) {
            int Lb = rowc * 512 + kt * 128 + lq * 32;
            f32x4 h0 = *reinterpret_cast<const f32x4*>(fB + (Lb ^ rswz));
            f32x4 h1 = *reinterpret_cast<const f32x4*>(fB + ((Lb + 16) ^ rswz));
            bf16x8 bfr;
            bfr[0] = (__bf16)h0[0]; bfr[1] = (__bf16)h0[1];
            bfr[2] = (__bf16)h0[2]; bfr[3] = (__bf16)h0[3];
            bfr[4] = (__bf16)h1[0]; bfr[5] = (__bf16)h1[1];
            bfr[6] = (__bf16)h1[2]; bfr[7] = (__bf16)h1[3];
            acc = __builtin_amdgcn_mfma_f32_16x16x32_bf16(af[kt], bfr, acc, 0, 0, 0);
        }
#pragma unroll
        for (int r = 0; r < 4; ++r) {
            int m = m0 + lq * 4 + r;          // hw row of S
            if (m < 49 && row < 49) Xrow[m * 49 + row] = f2b(acc[r]);
        }
    }
}

// ---------------------------------------------------------------------------
// gemm1 body: H = gelu(X @ W1 + b1). M=CH, N=384, K=2432.
// BM=64, BN=128, BK=32. local grid (M/64)*3. 4 waves 2x2, wave tile 32x64.
// LDS double-buffer + register prefetch; ONE barrier per K-iteration.
// Prefetch loads are issued AFTER the barrier so the implicit vmcnt(0)
// drain at __syncthreads never stalls on them; they are waited (by the
// compiler's dependency waitcnt) only at the NXT-buffer LDS write, by which
// time ds_read+MFMA of the current tile has covered most of the latency.
// ---------------------------------------------------------------------------
__device__ __forceinline__ void gemm1_body(unsigned short* sm, int lb,
    const unsigned short* __restrict__ X,    // [M, 2432] bf16
    const unsigned short* __restrict__ W1T,  // [384, 2432] bf16
    const float* __restrict__ b1,            // [384] fp32
    unsigned short* __restrict__ Hout)       // [M, 384] bf16
{
    const int tid = threadIdx.x;
    const int bm = lb / 3, bn = lb - bm * 3;
    const int m_base = bm * 64, n_base = bn * 128;

    const int wave = tid >> 6, lane = tid & 63;
    const int wm = wave >> 1, wn = wave & 1;
    const int la = lane & 15, lq = lane >> 4;

    f32x4 acc[2][4];
#pragma unroll
    for (int i = 0; i < 2; ++i)
#pragma unroll
        for (int j = 0; j < 4; ++j) acc[i][j] = {0.f, 0.f, 0.f, 0.f};

    const int a_row = tid >> 2, c8 = (tid & 3) * 8;
    const unsigned short* Xp  = X   + (size_t)(m_base + a_row) * KPAD + c8;
    const unsigned short* Wp0 = W1T + (size_t)(n_base + a_row) * KPAD + c8;
    const unsigned short* Wp1 = Wp0 + (size_t)64 * KPAD;

    // prologue: tile 0 -> LDS buffer 0
    uint4 ra  = *reinterpret_cast<const uint4*>(Xp);
    uint4 rb0 = *reinterpret_cast<const uint4*>(Wp0);
    uint4 rb1 = *reinterpret_cast<const uint4*>(Wp1);
    *reinterpret_cast<uint4*>(&sm[a_row * 40 + c8])              = ra;
    *reinterpret_cast<uint4*>(&sm[2560 + a_row * 40 + c8])       = rb0;
    *reinterpret_cast<uint4*>(&sm[2560 + (a_row + 64) * 40 + c8]) = rb1;

    const int NT = KPAD / 32;   // 76
    for (int t = 0; t < NT; ++t) {
        unsigned short* CUR = sm + ((t & 1) ? 7680 : 0);
        unsigned short* NXT = sm + ((t & 1) ? 0 : 7680);
        __syncthreads();                 // CUR writes visible; NXT reads done
        const bool pf = (t + 1 < NT);
        if (pf) {
            const int k1 = (t + 1) * 32;
            ra  = *reinterpret_cast<const uint4*>(Xp  + k1);
            rb0 = *reinterpret_cast<const uint4*>(Wp0 + k1);
            rb1 = *reinterpret_cast<const uint4*>(Wp1 + k1);
        }
        bf16x8 af[2], bfr[4];
#pragma unroll
        for (int mt = 0; mt < 2; ++mt)
            af[mt] = *reinterpret_cast<const bf16x8*>(&CUR[(wm * 32 + mt * 16 + la) * 40 + lq * 8]);
#pragma unroll
        for (int nt = 0; nt < 4; ++nt)
            bfr[nt] = *reinterpret_cast<const bf16x8*>(&CUR[2560 + (wn * 64 + nt * 16 + la) * 40 + lq * 8]);
#pragma unroll
        for (int mt = 0; mt < 2; ++mt)
#pragma unroll
            for (int nt = 0; nt < 4; ++nt)
                acc[mt][nt] = __builtin_amdgcn_mfma_f32_16x16x32_bf16(af[mt], bfr[nt], acc[mt][nt], 0, 0, 0);
        if (pf) {
            *reinterpret_cast<uint4*>(&NXT[a_row * 40 + c8])               = ra;
            *reinterpret_cast<uint4*>(&NXT[2560 + a_row * 40 + c8])        = rb0;
            *reinterpret_cast<uint4*>(&NXT[2560 + (a_row + 64) * 40 + c8]) = rb1;
        }
    }
#pragma unroll
    for (int mt = 0; mt < 2; ++mt) {
#pragma unroll
        for (int nt = 0; nt < 4; ++nt) {
            int nn = n_base + wn * 64 + nt * 16 + la;
            float bias = b1[nn];
#pragma unroll
            for (int r = 0; r < 4; ++r) {
                int m = m_base + wm * 32 + mt * 16 + lq * 4 + r;
                float v = acc[mt][nt][r] + bias;
                v = 0.5f * v * (1.0f + erff(v * 0.70710678118654752f));  // exact GELU
                Hout[(size_t)m * 384 + nn] = f2b(v);
            }
        }
    }
}

// ---------------------------------------------------------------------------
// gemm2 body: out[n0+m, lvl*256 + nn] = H @ W2 + b2 (fp32 out).
// M=CH, N=256, K=384. BM=64, BN=128. local grid (M/64)*2. Same dbuf template.
// ---------------------------------------------------------------------------
__device__ __forceinline__ void gemm2_body(unsigned short* sm, int lb,
    const unsigned short* __restrict__ Hin,  // [M, 384] bf16
    const unsigned short* __restrict__ W2T,  // [256, 384] bf16
    const float* __restrict__ b2,            // [256] fp32
    float* __restrict__ out,                 // [4096, 1024] fp32
    int lvl, int n0)
{
    const int tid = threadIdx.x;
    const int bm = lb >> 1, bn = lb & 1;
    const int m_base = bm * 64, n_base = bn * 128;

    const int wave = tid >> 6, lane = tid & 63;
    const int wm = wave >> 1, wn = wave & 1;
    const int la = lane & 15, lq = lane >> 4;

    f32x4 acc[2][4];
#pragma unroll
    for (int i = 0; i < 2; ++i)
#pragma unroll
        for (int j = 0; j < 4; ++j) acc[i][j] = {0.f, 0.f, 0.f, 0.f};

    const int a_row = tid >> 2, c8 = (tid & 3) * 8;
    const unsigned short* Hp  = Hin + (size_t)(m_base + a_row) * 384 + c8;
    const unsigned short* Wp0 = W2T + (size_t)(n_base + a_row) * 384 + c8;
    const unsigned short* Wp1 = Wp0 + (size_t)64 * 384;

    uint4 ra  = *reinterpret_cast<const uint4*>(Hp);
    uint4 rb0 = *reinterpret_cast<const uint4*>(Wp0);
    uint4 rb1 = *reinterpret_cast<const uint4*>(Wp1);
    *reinterpret_cast<uint4*>(&sm[a_row * 40 + c8])               = ra;
    *reinterpret_cast<uint4*>(&sm[2560 + a_row * 40 + c8])        = rb0;
    *reinterpret_cast<uint4*>(&sm[2560 + (a_row + 64) * 40 + c8]) = rb1;

    const int NT = 384 / 32;   // 12
    for (int t = 0; t < NT; ++t) {
        unsigned short* CUR = sm + ((t & 1) ? 7680 : 0);
        unsigned short* NXT = sm + ((t & 1) ? 0 : 7680);
        __syncthreads();
        const bool pf = (t + 1 < NT);
        if (pf) {
            const int k1 = (t + 1) * 32;
            ra  = *reinterpret_cast<const uint4*>(Hp  + k1);
            rb0 = *reinterpret_cast<const uint4*>(Wp0 + k1);
            rb1 = *reinterpret_cast<const uint4*>(Wp1 + k1);
        }
        bf16x8 af[2], bfr[4];
#pragma unroll
        for (int mt = 0; mt < 2; ++mt)
            af[mt] = *reinterpret_cast<const bf16x8*>(&CUR[(wm * 32 + mt * 16 + la) * 40 + lq * 8]);
#pragma unroll
        for (int nt = 0; nt < 4; ++nt)
            bfr[nt] = *reinterpret_cast<const bf16x8*>(&CUR[2560 + (wn * 64 + nt * 16 + la) * 40 + lq * 8]);
#pragma unroll
        for (int mt = 0; mt < 2; ++mt)
#pragma unroll
            for (int nt = 0; nt < 4; ++nt)
                acc[mt][nt] = __builtin_amdgcn_mfma_f32_16x16x32_bf16(af[mt], bfr[nt], acc[mt][nt], 0, 0, 0);
        if (pf) {
            *reinterpret_cast<uint4*>(&NXT[a_row * 40 + c8])               = ra;
            *reinterpret_cast<uint4*>(&NXT[2560 + a_row * 40 + c8])        = rb0;
            *reinterpret_cast<uint4*>(&NXT[2560 + (a_row + 64) * 40 + c8]) = rb1;
        }
    }
#pragma unroll
    for (int mt = 0; mt < 2; ++mt) {
#pragma unroll
        for (int nt = 0; nt < 4; ++nt) {
            int nn = n_base + wn * 64 + nt * 16 + la;
            float bias = b2[nn];
#pragma unroll
            for (int r = 0; r < 4; ++r) {
                int m = m_base + wm * 32 + mt * 16 + lq * 4 + r;
                out[(size_t)(n0 + m) * 1024 + lvl * 256 + nn] = acc[mt][nt][r] + bias;
            }
        }
    }
}

// ---------------------------------------------------------------------------
// Fused heterogeneous stage kernel. Gemm blocks dispatch FIRST so the
// previous stage's gemms start immediately, then the corr flood.
// blocks [0,nG1) -> gemm1(t-1); [nG1,nG1+nG2) -> gemm2(t-2); rest -> corr(t).
// ---------------------------------------------------------------------------
__global__ __launch_bounds__(256, 4) void k_stage(
    const unsigned short* __restrict__ fm, const float* __restrict__ tfp,
    const float* __restrict__ coords,
    unsigned short* __restrict__ Xd, int W, int H, float scale, int n0c,
    const unsigned short* __restrict__ Xs, const unsigned short* __restrict__ W1T,
    const float* __restrict__ b1, unsigned short* __restrict__ Hd, int nG1,
    const unsigned short* __restrict__ Hs, const unsigned short* __restrict__ W2T,
    const float* __restrict__ b2, float* __restrict__ out, int lvl2, int n0g2,
    int nG2)
{
    __shared__ __align__(16) unsigned short sm[SM_SHORTS];
    const int bb = blockIdx.x;
    if (bb < nG1) {
        gemm1_body(sm, bb, Xs, W1T, b1, Hd);
    } else if (bb < nG1 + nG2) {
        gemm2_body(sm, bb - nG1, Hs, W2T, b2, out, lvl2, n0g2);
    } else {
        corr_body(sm, bb - nG1 - nG2, fm, tfp, coords, Xd, W, H, scale, n0c);
    }
}

// ---------------------------------------------------------------------------
extern "C" void kernel_launch(void* const* d_in, const int* in_sizes, int n_in,
                              void* d_out, int out_size, void* d_ws, size_t ws_size,
                              hipStream_t stream)
{
    const float *fm[4], *tf[4], *coords, *w1, *b1, *w2, *b2;
    if (n_in >= 13 && in_sizes[0] == 384) {
        // alphabetical: b1,b2,coords,fmaps0-3,tfeat0-3,w1,w2
        b1 = (const float*)d_in[0]; b2 = (const float*)d_in[1];
        coords = (const float*)d_in[2];
        for (int i = 0; i < 4; ++i) fm[i] = (const float*)d_in[3 + i];
        for (int i = 0; i < 4; ++i) tf[i] = (const float*)d_in[7 + i];
        w1 = (const float*)d_in[11]; w2 = (const float*)d_in[12];
    } else if (n_in >= 13 && in_sizes[1] == 25690112) {
        // setup_inputs dict order: fmaps0,tfeat0,...,coords,w1,b1,w2,b2
        for (int i = 0; i < 4; ++i) { fm[i] = (const float*)d_in[2 * i];
                                      tf[i] = (const float*)d_in[2 * i + 1]; }
        coords = (const float*)d_in[8];
        w1 = (const float*)d_in[9];  b1 = (const float*)d_in[10];
        w2 = (const float*)d_in[11]; b2 = (const float*)d_in[12];
    } else {
        // reference-arg order: fmaps0-3, coords, tfeat0-3, w1, b1, w2, b2
        for (int i = 0; i < 4; ++i) fm[i] = (const float*)d_in[i];
        coords = (const float*)d_in[4];
        for (int i = 0; i < 4; ++i) tf[i] = (const float*)d_in[5 + i];
        w1 = (const float*)d_in[9];  b1 = (const float*)d_in[10];
        w2 = (const float*)d_in[11]; b2 = (const float*)d_in[12];
    }

    const int   cW[4]   = {128, 64, 32, 16};
    const int   cH[4]   = {96, 48, 24, 12};
    const int   cOff[4] = {0, 1572864, 1966080, 2064384};
    const float cS[4]   = {1.0f, 0.5f, 0.25f, 0.125f};

    // ---- workspace-adaptive layout --------------------------------------
    int CH, nbuf;
    if (ws_size >= (size_t)52379648)      { CH = 4096; nbuf = 2; }
    else if (ws_size >= (size_t)17776640) { CH = 1024; nbuf = 2; }
    else                                  { CH = 1024; nbuf = 1; }

    char* ws = (char*)d_ws;
    size_t xBytes = (size_t)CH * KPAD * 2;
    size_t hBytes = (size_t)CH * 384 * 2;
    size_t off = 0;
    unsigned short* Xb[2]; unsigned short* Hb[2];
    Xb[0] = (unsigned short*)(ws + off); off += xBytes;
    if (nbuf == 2) { Xb[1] = (unsigned short*)(ws + off); off += xBytes; }
    else           { Xb[1] = Xb[0]; }
    Hb[0] = (unsigned short*)(ws + off); off += hBytes;
    if (nbuf == 2) { Hb[1] = (unsigned short*)(ws + off); off += hBytes; }
    else           { Hb[1] = Hb[0]; }
    unsigned short* fmapT = (unsigned short*)(ws + off); off += 4177920;
    unsigned short* W1T   = (unsigned short*)(ws + off); off += 1867776;
    unsigned short* W2T   = (unsigned short*)(ws + off); off += 196608;

    hipLaunchKernelGGL(k_prep, dim3(12192), dim3(256), 0, stream,
                       fm[0], fm[1], fm[2], fm[3], w1, w2, fmapT, W1T, W2T);

    const int S   = (CH == 4096) ? 4 : 16;     // number of (level,chunk) stages
    const int nG1 = (CH / 64) * 3;             // gemm1 blocks per stage
    const int nG2 = (CH / 64) * 2;             // gemm2 blocks per stage

    if (nbuf == 2) {
        // Pipelined: launch t = corr(t) || gemm1(t-1) || gemm2(t-2).
        for (int t = 0; t < S + 2; ++t) {
            const int s0 = t, s1 = t - 1, s2 = t - 2;
            const int nc = (s0 < S) ? CH : 0;
            const int n1 = (s1 >= 0 && s1 < S) ? nG1 : 0;
            const int n2 = (s2 >= 0 && s2 < S) ? nG2 : 0;
            const int l0 = nc ? ((CH == 4096) ? s0 : (s0 >> 2)) : 0;
            const int l2 = n2 ? ((CH == 4096) ? s2 : (s2 >> 2)) : 0;
            const int n00 = (nc && CH != 4096) ? ((s0 & 3) << 10) : 0;
            const int n02 = (n2 && CH != 4096) ? ((s2 & 3) << 10) : 0;
            hipLaunchKernelGGL(k_stage, dim3(nc + n1 + n2), dim3(256), 0, stream,
                fmapT + cOff[l0], tf[l0], coords,
                Xb[t & 1], cW[l0], cH[l0], cS[l0], n00,
                Xb[(t + 1) & 1], W1T, b1, Hb[(t + 1) & 1], n1,
                Hb[t & 1], W2T, b2, (float*)d_out, l2, n02, n2);
        }
    } else {
        // Sequential fallback (single X/H buffers).
        for (int s = 0; s < S; ++s) {
            const int l = s >> 2, n0 = (s & 3) << 10;
            hipLaunchKernelGGL(k_stage, dim3(CH), dim3(256), 0, stream,
                fmapT + cOff[l], tf[l], coords,
                Xb[0], cW[l], cH[l], cS[l], n0,
                Xb[0], W1T, b1, Hb[0], 0,
                Hb[0], W2T, b2, (float*)d_out, l, n0, 0);
            hipLaunchKernelGGL(k_stage, dim3(nG1), dim3(256), 0, stream,
                fmapT, tf[0], coords, Xb[0], 0, 0, 0.f, 0,
                Xb[0], W1T, b1, Hb[0], nG1,
                Hb[0], W2T, b2, (float*)d_out, l, n0, 0);
            hipLaunchKernelGGL(k_stage, dim3(nG2), dim3(256), 0, stream,
                fmapT, tf[0], coords, Xb[0], 0, 0, 0.f, 0,
                Xb[0], W1T, b1, Hb[0], 0,
                Hb[0], W2T, b2, (float*)d_out, l, n0, nG2);
        }
    }
}